// Round 5
// baseline (229.067 us; speedup 1.0000x reference)
//
#include <hip/hip_runtime.h>
#include <hip/hip_bf16.h>

namespace {
constexpr int S  = 4096;
constexpr int D  = 768;
constexpr int H  = 12;
constexpr int N3 = 2304;   // 3*D

typedef __bf16 bf16x4 __attribute__((ext_vector_type(4)));
typedef __bf16 bf16x8 __attribute__((ext_vector_type(8)));
typedef float  floatx4 __attribute__((ext_vector_type(4)));

// async global->LDS, 16B per lane; LDS dest = wave-uniform base + lane*16.
__device__ inline void glds16(const __bf16* g, __bf16* l) {
  __builtin_amdgcn_global_load_lds(
      (const __attribute__((address_space(1))) void*)(const void*)g,
      (__attribute__((address_space(3))) void*)(void*)l, 16, 0, 0);
}

// ---------------------------------------------------------------------------
// Kernel 0: merged converts. bid < 3072: x fp32 -> bf16 (1024 elems/block).
// Else: W [768][2304] fp32 -> WT [2304][768] bf16 via LDS tile transpose.
// ---------------------------------------------------------------------------
__global__ __launch_bounds__(256)
void convert_all(const float* __restrict__ x, __bf16* __restrict__ xb,
                 const float* __restrict__ W, __bf16* __restrict__ WT)
{
  const int bid = blockIdx.x;
  const int tid = threadIdx.x;
  if (bid < 3072) {
    const int i = (bid * 256 + tid) * 4;
    floatx4 v = *reinterpret_cast<const floatx4*>(x + i);
    bf16x4 b;
    #pragma unroll
    for (int e = 0; e < 4; ++e) b[e] = (__bf16)v[e];
    *reinterpret_cast<bf16x4*>(xb + i) = b;
  } else {
    __shared__ float T[64][65];
    const int b2 = bid - 3072;
    const int d0 = (b2 % 12) * 64, e0 = (b2 / 12) * 64;
    const int rr = tid >> 4, c4 = (tid & 15) * 4;
    #pragma unroll
    for (int it = 0; it < 4; ++it) {
      int d = it * 16 + rr;
      floatx4 v = *reinterpret_cast<const floatx4*>(W + (d0 + d) * N3 + e0 + c4);
      #pragma unroll
      for (int e = 0; e < 4; ++e) T[d][c4 + e] = v[e];
    }
    __syncthreads();
    #pragma unroll
    for (int it = 0; it < 4; ++it) {
      int e = it * 16 + rr;
      bf16x4 b;
      #pragma unroll
      for (int i = 0; i < 4; ++i) b[i] = (__bf16)T[c4 + i][e];
      *reinterpret_cast<bf16x4*>(WT + (e0 + e) * D + d0 + c4) = b;
    }
  }
}

// ---------------------------------------------------------------------------
// Kernel 1 (VERBATIM): QKV GEMM, 128x96 tile, grid 32x24 = 768 = 3/CU.
// glds16 + XOR swizzle, BK=64. Q/K direct stores; V via swizzled-LDS
// transpose (k-slot-permuted) then coalesced 16B vT stores.
// ---------------------------------------------------------------------------
__global__ __launch_bounds__(256)
void qkv_gemm(const __bf16* __restrict__ xb, const __bf16* __restrict__ WT,
              const float* __restrict__ bq, __bf16* __restrict__ Qb,
              __bf16* __restrict__ Kb, __bf16* __restrict__ vT)
{
  __shared__ __bf16 smem[14336];           // 28 KB: As(16K) | Bs(12K); vts(24K)
  __bf16* As = smem;                        // [128][64] swizzled
  __bf16* Bs = smem + 8192;                 // [96][64]  swizzled

  const int tid  = threadIdx.x;
  const int wave = tid >> 6, lane = tid & 63;
  const int quad = lane >> 4, l16 = lane & 15;
  const int m_base = (wave >> 1) * 64;
  const int n_base = (wave & 1) * 48;
  const int bm = blockIdx.x, bn = blockIdx.y;
  const int srow = lane >> 3, sg = lane & 7;

  floatx4 acc[4][3];
  #pragma unroll
  for (int i = 0; i < 4; ++i)
    #pragma unroll
    for (int j = 0; j < 3; ++j) acc[i][j] = (floatx4){0.f, 0.f, 0.f, 0.f};

  for (int ks = 0; ks < 12; ++ks) {
    const int k0 = ks * 64;
    __syncthreads();
    #pragma unroll
    for (int it = 0; it < 4; ++it) {
      int rbase = it * 32 + wave * 8;
      int row = rbase + srow;
      glds16(xb + (size_t)(bm * 128 + row) * D + k0 + (sg ^ (row & 7)) * 8,
             As + rbase * 64);
    }
    #pragma unroll
    for (int it = 0; it < 3; ++it) {
      int rbase = it * 32 + wave * 8;
      int row = rbase + srow;
      glds16(WT + (size_t)(bn * 96 + row) * D + k0 + (sg ^ (row & 7)) * 8,
             Bs + rbase * 64);
    }
    __syncthreads();

    bf16x8 af[4][2], bfr[3][2];
    #pragma unroll
    for (int mt = 0; mt < 4; ++mt)
      #pragma unroll
      for (int kt = 0; kt < 2; ++kt) {
        int m = m_base + mt * 16 + l16;
        af[mt][kt] = *reinterpret_cast<const bf16x8*>(
            &As[m * 64 + ((((kt << 2) | quad) ^ (l16 & 7)) << 3)]);
      }
    #pragma unroll
    for (int nt = 0; nt < 3; ++nt)
      #pragma unroll
      for (int kt = 0; kt < 2; ++kt) {
        int n = n_base + nt * 16 + l16;
        bfr[nt][kt] = *reinterpret_cast<const bf16x8*>(
            &Bs[n * 64 + ((((kt << 2) | quad) ^ (l16 & 7)) << 3)]);
      }
    #pragma unroll
    for (int kt = 0; kt < 2; ++kt)
      #pragma unroll
      for (int mt = 0; mt < 4; ++mt)
        #pragma unroll
        for (int nt = 0; nt < 3; ++nt)
          acc[mt][nt] = __builtin_amdgcn_mfma_f32_16x16x32_bf16(
              af[mt][kt], bfr[nt][kt], acc[mt][nt], 0, 0, 0);
  }

  if (bn < 16) {
    #pragma unroll
    for (int nt = 0; nt < 3; ++nt) {
      int col = bn * 96 + n_base + nt * 16 + l16;
      float bias = bq[col];
      #pragma unroll
      for (int mt = 0; mt < 4; ++mt) {
        int row = bm * 128 + m_base + mt * 16 + quad * 4;
        #pragma unroll
        for (int r = 0; r < 4; ++r) {
          __bf16 v = (__bf16)(acc[mt][nt][r] + bias);
          if (bn < 8) Qb[(row + r) * D + col] = v;
          else        Kb[(row + r) * D + (col - D)] = v;
        }
      }
    }
  } else {
    __syncthreads();
    __bf16* vts = smem;   // [w 96][t 128], addr = w*128 + (pos ^ ((w&7)<<3))
    #pragma unroll
    for (int nt = 0; nt < 3; ++nt) {
      int wl = n_base + nt * 16 + l16;
      float bias = bq[bn * 96 + wl];
      int sw = (wl & 7) << 3;
      #pragma unroll
      for (int mt = 0; mt < 4; ++mt) {
        #pragma unroll
        for (int r = 0; r < 4; ++r) {
          int tl = m_base + mt * 16 + quad * 4 + r;
          int pos = (tl & ~31) | (quad << 3) | ((tl & 16) >> 2) | r;
          vts[wl * 128 + (pos ^ sw)] = (__bf16)(acc[mt][nt][r] + bias);
        }
      }
    }
    __syncthreads();
    const int w0g = bn * 96 - 2 * D;
    #pragma unroll
    for (int it = 0; it < 6; ++it) {
      int c = it * 256 + tid;
      int wl = c >> 4, t0 = (c & 15) * 8;
      bf16x8 v = *reinterpret_cast<const bf16x8*>(
          &vts[wl * 128 + (t0 ^ ((wl & 7) << 3))]);
      *reinterpret_cast<bf16x8*>(
          &vT[(size_t)(w0g + wl) * S + bm * 128 + t0]) = v;
    }
  }
}

// ---------------------------------------------------------------------------
// Kernel 2: flash attention, 4-wave (256-thread) blocks — R2 shape — with the
// barrier count cut 3 -> 1 per step:
//  * V is consumed by exactly ONE wave per element (t-slot contains th), so V
//    skips LDS entirely: per-wave REGISTER prefetch, 8 x 16B loads/step,
//    loaded one full step ahead. The GEMM's vT t-permutation is already
//    MFMA-fragment order and the LDS XOR swizzle cancels against the staging
//    swizzle, so vf = vT[(qcol+w)*S + j*128 + (th*8+u*4+quad)*8 ..+7] directly.
//  * K keeps the glds ping-pong; only B1 remains (protects buffer swap +
//    visibility). B_mid/B2 deleted.
//  * pf packed directly in softmax (no ps->pf concat), R4-validated algebra.
//  vmcnt ledger (per wave/iter: mask 4, stageK 4, vf 8 = 16 VMEM, order
//  pinned by sched_barrier(0)):
//    steady top of iter j: outstanding [K(j)4, vf(j)8]; issue mask 4 -> 16;
//      explicit vmcnt(12) drains K(j).  B1.  stageK(j+1) -> +4.
//    softmax mask-use: compiler waits (newer-than-mask = K(j+1)4) ->
//      vmcnt(4): drains vf(j)+mask, K(j+1) stays in flight.
//    PV on registers (no barrier).  loadV(j+1) -> [K(j+1)4, vf(j+1)8]. OK.
//    Prologue (stageK(0) then loadV(0)) and j=31 (no issues) both satisfy
//    the same counts.
//  LDS: K0|K1 = 32768 B only; reduction (Lo 16896B + Ll 256B) aliases in.
//  No launch_bounds min-arg (R3 spill lesson): ~130 VGPR -> 3 waves/SIMD.
// ---------------------------------------------------------------------------
__global__ __launch_bounds__(256)
void attention(const __bf16* __restrict__ Qb, const __bf16* __restrict__ Kb,
               const __bf16* __restrict__ vT, const float* __restrict__ mask,
               float* __restrict__ out)
{
  __shared__ char smem[32768];   // K ping-pong; reduction aliases after drain

  const int tid  = threadIdx.x;
  const int wave = tid >> 6, lane = tid & 63;
  const int quad = lane >> 4, l16 = lane & 15;
  const int qh = wave >> 1;       // q-half
  const int th = wave & 1;        // t-half
  const int qb = blockIdx.x, h = blockIdx.y;
  const int q0 = qb * 64;
  const int qcol = h * 64;
  const int srow = lane >> 3, sg = lane & 7;

  bf16x8 qf[2][2];
  #pragma unroll
  for (int nt = 0; nt < 2; ++nt)
    #pragma unroll
    for (int kt = 0; kt < 2; ++kt)
      qf[nt][kt] = *reinterpret_cast<const bf16x8*>(
          Qb + (q0 + qh * 32 + nt * 16 + l16) * D + qcol + kt * 32 + quad * 8);

  floatx4 accO[4][2];
  #pragma unroll
  for (int wt = 0; wt < 4; ++wt)
    #pragma unroll
    for (int nt = 0; nt < 2; ++nt) accO[wt][nt] = (floatx4){0.f, 0.f, 0.f, 0.f};
  floatx4 accL[2];
  accL[0] = (floatx4){0.f, 0.f, 0.f, 0.f};
  accL[1] = (floatx4){0.f, 0.f, 0.f, 0.f};
  bf16x8 ones;
  #pragma unroll
  for (int e = 0; e < 8; ++e) ones[e] = (__bf16)1.0f;

  // K tile [128][64]: 256 lanes x 16B = 32 rows/round, 4 rounds.
  auto stageK = [&](int j, __bf16* dst) {
    #pragma unroll
    for (int it = 0; it < 4; ++it) {
      int rbase = it * 32 + wave * 8;
      int t = rbase + srow;
      glds16(Kb + (size_t)(j * 128 + t) * D + qcol + (sg ^ (t & 7)) * 8,
             dst + rbase * 64);
    }
  };

  // V fragments: per-wave registers, fragment-ready straight from vT.
  bf16x8 vf[2][4];
  auto loadV = [&](int j) {
    #pragma unroll
    for (int u = 0; u < 2; ++u)
      #pragma unroll
      for (int wt = 0; wt < 4; ++wt)
        vf[u][wt] = *reinterpret_cast<const bf16x8*>(
            vT + (size_t)(qcol + wt * 16 + l16) * S + j * 128
               + (th * 8 + u * 4 + quad) * 8);
  };

  // prologue: K(0) glds (oldest), then V(0) regs
  stageK(0, (__bf16*)smem);
  __builtin_amdgcn_sched_barrier(0);
  loadV(0);
  __builtin_amdgcn_sched_barrier(0);

  for (int j = 0; j < 32; ++j) {
    // mask loads for this step (issued before the counted wait)
    floatx4 mv[4];
    #pragma unroll
    for (int mt = 0; mt < 4; ++mt)
      mv[mt] = *reinterpret_cast<const floatx4*>(
          mask + j * 128 + th * 64 + mt * 16 + quad * 4);
    __builtin_amdgcn_sched_barrier(0);

    asm volatile("s_waitcnt vmcnt(12)" ::: "memory");  // own K(j) drained
    __builtin_amdgcn_s_barrier();                      // B1: K(j) visible
    __builtin_amdgcn_sched_barrier(0);

    if (j < 31)                                        // prefetch next K
      stageK(j + 1, (__bf16*)(smem + (((j + 1) & 1) << 14)));
    __builtin_amdgcn_sched_barrier(0);

    const __bf16* Kc = (const __bf16*)(smem + ((j & 1) << 14));

    // S^T = K Q^T ; P = exp2(scale*S + mask2), packed directly into pf.
    bf16x8 pf[2][2];
    #pragma unroll
    for (int mt = 0; mt < 4; ++mt) {
      int trow = th * 64 + mt * 16 + l16;
      bf16x8 kf[2];
      #pragma unroll
      for (int kt = 0; kt < 2; ++kt)
        kf[kt] = *reinterpret_cast<const bf16x8*>(
            &Kc[trow * 64 + ((((kt << 2) | quad) ^ (l16 & 7)) << 3)]);
      floatx4 am;   // (m-1)*10000*log2e ; exactly 0 when m==1
      #pragma unroll
      for (int r = 0; r < 4; ++r)
        am[r] = fmaf(mv[mt][r], 14426.9504f, -14426.9504f);
      #pragma unroll
      for (int nt = 0; nt < 2; ++nt) {
        floatx4 s = (floatx4){0.f, 0.f, 0.f, 0.f};
        #pragma unroll
        for (int kt = 0; kt < 2; ++kt)
          s = __builtin_amdgcn_mfma_f32_16x16x32_bf16(kf[kt], qf[nt][kt], s, 0, 0, 0);
        #pragma unroll
        for (int r = 0; r < 4; ++r)
          pf[mt >> 1][nt][(mt & 1) * 4 + r] = (__bf16)__builtin_amdgcn_exp2f(
              fmaf(s[r], 0.18033688f, am[r]));   // 0.125*log2e
      }
    }

    // O^T += V^T P^T from registers — no barrier needed.
    #pragma unroll
    for (int u = 0; u < 2; ++u) {
      #pragma unroll
      for (int nt = 0; nt < 2; ++nt)
        accL[nt] = __builtin_amdgcn_mfma_f32_16x16x32_bf16(
            ones, pf[u][nt], accL[nt], 0, 0, 0);
      #pragma unroll
      for (int wt = 0; wt < 4; ++wt)
        #pragma unroll
        for (int nt = 0; nt < 2; ++nt)
          accO[wt][nt] = __builtin_amdgcn_mfma_f32_16x16x32_bf16(
              vf[u][wt], pf[u][nt], accO[wt][nt], 0, 0, 0);
    }

    __builtin_amdgcn_sched_barrier(0);
    if (j < 31) loadV(j + 1);                          // prefetch next V regs
    __builtin_amdgcn_sched_barrier(0);
  }

  // l for q = nt*16+l16 over this wave's 64 t: all 4 acc rows identical.
  float l_lane[2] = {accL[0][0], accL[1][0]};

  // ---- cross-wave reduction over t-halves ----
  float* Lo = (float*)smem;              // 2 x [64][33] f32 = 16896 B
  float* Ll = (float*)(smem + 16896);    // 64 f32 l partials
  __syncthreads();   // full drain; safe to alias over K buffers
  if (th == 1) {
    float* dst = Lo + qh * (64 * 33);
    #pragma unroll
    for (int wt = 0; wt < 4; ++wt)
      #pragma unroll
      for (int nt = 0; nt < 2; ++nt)
        #pragma unroll
        for (int r = 0; r < 4; ++r)
          dst[(wt * 16 + quad * 4 + r) * 33 + nt * 16 + l16] = accO[wt][nt][r];
    if (quad == 0) {
      #pragma unroll
      for (int nt = 0; nt < 2; ++nt)
        Ll[qh * 32 + nt * 16 + l16] = l_lane[nt];
    }
  }
  __syncthreads();
  if (th == 0) {
    const float* src = Lo + qh * (64 * 33);
    float l_tot[2];
    #pragma unroll
    for (int nt = 0; nt < 2; ++nt)
      l_tot[nt] = l_lane[nt] + Ll[qh * 32 + nt * 16 + l16];
    #pragma unroll
    for (int wt = 0; wt < 4; ++wt)
      #pragma unroll
      for (int nt = 0; nt < 2; ++nt) {
        floatx4 o;
        #pragma unroll
        for (int r = 0; r < 4; ++r)
          o[r] = (accO[wt][nt][r] +
                  src[(wt * 16 + quad * 4 + r) * 33 + nt * 16 + l16]) / l_tot[nt];
        int row = q0 + qh * 32 + nt * 16 + l16;
        int col = qcol + wt * 16 + quad * 4;
        *reinterpret_cast<floatx4*>(&out[row * D + col]) = o;
      }
  }
}

} // namespace

extern "C" void kernel_launch(void* const* d_in, const int* in_sizes, int n_in,
                              void* d_out, int out_size, void* d_ws, size_t ws_size,
                              hipStream_t stream) {
  const float *x = nullptr, *mask = nullptr, *Wq = nullptr, *bq = nullptr;
  for (int i = 0; i < n_in; ++i) {
    switch (in_sizes[i]) {
      case 3145728: x    = (const float*)d_in[i]; break;
      case 4096:    mask = (const float*)d_in[i]; break;
      case 1769472: Wq   = (const float*)d_in[i]; break;
      case 2304:    bq   = (const float*)d_in[i]; break;
      default: break;
    }
  }

  __bf16* xb = (__bf16*)d_out;               // bf16 scratch in d_out
  __bf16* WT = xb + (size_t)S * D;
  __bf16* Qb = (__bf16*)d_ws;
  __bf16* Kb = Qb + (size_t)S * D;
  __bf16* vT = Kb + (size_t)S * D;

  convert_all<<<3072 + 432, 256, 0, stream>>>(x, xb, Wq, WT);
  qkv_gemm   <<<dim3(S / 128, N3 / 96), 256, 0, stream>>>(xb, WT, bq, Qb, Kb, vT);
  attention  <<<dim3(S / 64, H), 256, 0, stream>>>(Qb, Kb, vT, mask, (float*)d_out);
}

// Round 6
// 165.284 us; speedup vs baseline: 1.3859x; 1.3859x over previous
//
#include <hip/hip_runtime.h>
#include <hip/hip_bf16.h>

namespace {
constexpr int S  = 4096;
constexpr int D  = 768;
constexpr int H  = 12;
constexpr int N3 = 2304;   // 3*D

typedef __bf16 bf16x4 __attribute__((ext_vector_type(4)));
typedef __bf16 bf16x8 __attribute__((ext_vector_type(8)));
typedef float  floatx4 __attribute__((ext_vector_type(4)));

// async global->LDS, 16B per lane; LDS dest = wave-uniform base + lane*16.
__device__ inline void glds16(const __bf16* g, __bf16* l) {
  __builtin_amdgcn_global_load_lds(
      (const __attribute__((address_space(1))) void*)(const void*)g,
      (__attribute__((address_space(3))) void*)(void*)l, 16, 0, 0);
}

// ---------------------------------------------------------------------------
// Kernel 0: merged converts. bid < 3072: x fp32 -> bf16 (1024 elems/block).
// Else: W [768][2304] fp32 -> WT [2304][768] bf16 via LDS tile transpose.
// ---------------------------------------------------------------------------
__global__ __launch_bounds__(256)
void convert_all(const float* __restrict__ x, __bf16* __restrict__ xb,
                 const float* __restrict__ W, __bf16* __restrict__ WT)
{
  const int bid = blockIdx.x;
  const int tid = threadIdx.x;
  if (bid < 3072) {
    const int i = (bid * 256 + tid) * 4;
    floatx4 v = *reinterpret_cast<const floatx4*>(x + i);
    bf16x4 b;
    #pragma unroll
    for (int e = 0; e < 4; ++e) b[e] = (__bf16)v[e];
    *reinterpret_cast<bf16x4*>(xb + i) = b;
  } else {
    __shared__ float T[64][65];
    const int b2 = bid - 3072;
    const int d0 = (b2 % 12) * 64, e0 = (b2 / 12) * 64;
    const int rr = tid >> 4, c4 = (tid & 15) * 4;
    #pragma unroll
    for (int it = 0; it < 4; ++it) {
      int d = it * 16 + rr;
      floatx4 v = *reinterpret_cast<const floatx4*>(W + (d0 + d) * N3 + e0 + c4);
      #pragma unroll
      for (int e = 0; e < 4; ++e) T[d][c4 + e] = v[e];
    }
    __syncthreads();
    #pragma unroll
    for (int it = 0; it < 4; ++it) {
      int e = it * 16 + rr;
      bf16x4 b;
      #pragma unroll
      for (int i = 0; i < 4; ++i) b[i] = (__bf16)T[c4 + i][e];
      *reinterpret_cast<bf16x4*>(WT + (e0 + e) * D + d0 + c4) = b;
    }
  }
}

// ---------------------------------------------------------------------------
// Kernel 1 (VERBATIM): QKV GEMM, 128x96 tile, grid 32x24 = 768 = 3/CU.
// glds16 + XOR swizzle, BK=64. Q/K direct stores; V via swizzled-LDS
// transpose (k-slot-permuted) then coalesced 16B vT stores.
// ---------------------------------------------------------------------------
__global__ __launch_bounds__(256)
void qkv_gemm(const __bf16* __restrict__ xb, const __bf16* __restrict__ WT,
              const float* __restrict__ bq, __bf16* __restrict__ Qb,
              __bf16* __restrict__ Kb, __bf16* __restrict__ vT)
{
  __shared__ __bf16 smem[14336];           // 28 KB: As(16K) | Bs(12K); vts(24K)
  __bf16* As = smem;                        // [128][64] swizzled
  __bf16* Bs = smem + 8192;                 // [96][64]  swizzled

  const int tid  = threadIdx.x;
  const int wave = tid >> 6, lane = tid & 63;
  const int quad = lane >> 4, l16 = lane & 15;
  const int m_base = (wave >> 1) * 64;
  const int n_base = (wave & 1) * 48;
  const int bm = blockIdx.x, bn = blockIdx.y;
  const int srow = lane >> 3, sg = lane & 7;

  floatx4 acc[4][3];
  #pragma unroll
  for (int i = 0; i < 4; ++i)
    #pragma unroll
    for (int j = 0; j < 3; ++j) acc[i][j] = (floatx4){0.f, 0.f, 0.f, 0.f};

  for (int ks = 0; ks < 12; ++ks) {
    const int k0 = ks * 64;
    __syncthreads();
    #pragma unroll
    for (int it = 0; it < 4; ++it) {
      int rbase = it * 32 + wave * 8;
      int row = rbase + srow;
      glds16(xb + (size_t)(bm * 128 + row) * D + k0 + (sg ^ (row & 7)) * 8,
             As + rbase * 64);
    }
    #pragma unroll
    for (int it = 0; it < 3; ++it) {
      int rbase = it * 32 + wave * 8;
      int row = rbase + srow;
      glds16(WT + (size_t)(bn * 96 + row) * D + k0 + (sg ^ (row & 7)) * 8,
             Bs + rbase * 64);
    }
    __syncthreads();

    bf16x8 af[4][2], bfr[3][2];
    #pragma unroll
    for (int mt = 0; mt < 4; ++mt)
      #pragma unroll
      for (int kt = 0; kt < 2; ++kt) {
        int m = m_base + mt * 16 + l16;
        af[mt][kt] = *reinterpret_cast<const bf16x8*>(
            &As[m * 64 + ((((kt << 2) | quad) ^ (l16 & 7)) << 3)]);
      }
    #pragma unroll
    for (int nt = 0; nt < 3; ++nt)
      #pragma unroll
      for (int kt = 0; kt < 2; ++kt) {
        int n = n_base + nt * 16 + l16;
        bfr[nt][kt] = *reinterpret_cast<const bf16x8*>(
            &Bs[n * 64 + ((((kt << 2) | quad) ^ (l16 & 7)) << 3)]);
      }
    #pragma unroll
    for (int kt = 0; kt < 2; ++kt)
      #pragma unroll
      for (int mt = 0; mt < 4; ++mt)
        #pragma unroll
        for (int nt = 0; nt < 3; ++nt)
          acc[mt][nt] = __builtin_amdgcn_mfma_f32_16x16x32_bf16(
              af[mt][kt], bfr[nt][kt], acc[mt][nt], 0, 0, 0);
  }

  if (bn < 16) {
    #pragma unroll
    for (int nt = 0; nt < 3; ++nt) {
      int col = bn * 96 + n_base + nt * 16 + l16;
      float bias = bq[col];
      #pragma unroll
      for (int mt = 0; mt < 4; ++mt) {
        int row = bm * 128 + m_base + mt * 16 + quad * 4;
        #pragma unroll
        for (int r = 0; r < 4; ++r) {
          __bf16 v = (__bf16)(acc[mt][nt][r] + bias);
          if (bn < 8) Qb[(row + r) * D + col] = v;
          else        Kb[(row + r) * D + (col - D)] = v;
        }
      }
    }
  } else {
    __syncthreads();
    __bf16* vts = smem;   // [w 96][t 128], addr = w*128 + (pos ^ ((w&7)<<3))
    #pragma unroll
    for (int nt = 0; nt < 3; ++nt) {
      int wl = n_base + nt * 16 + l16;
      float bias = bq[bn * 96 + wl];
      int sw = (wl & 7) << 3;
      #pragma unroll
      for (int mt = 0; mt < 4; ++mt) {
        #pragma unroll
        for (int r = 0; r < 4; ++r) {
          int tl = m_base + mt * 16 + quad * 4 + r;
          int pos = (tl & ~31) | (quad << 3) | ((tl & 16) >> 2) | r;
          vts[wl * 128 + (pos ^ sw)] = (__bf16)(acc[mt][nt][r] + bias);
        }
      }
    }
    __syncthreads();
    const int w0g = bn * 96 - 2 * D;
    #pragma unroll
    for (int it = 0; it < 6; ++it) {
      int c = it * 256 + tid;
      int wl = c >> 4, t0 = (c & 15) * 8;
      bf16x8 v = *reinterpret_cast<const bf16x8*>(
          &vts[wl * 128 + (t0 ^ ((wl & 7) << 3))]);
      *reinterpret_cast<bf16x8*>(
          &vT[(size_t)(w0g + wl) * S + bm * 128 + t0]) = v;
    }
  }
}

// ---------------------------------------------------------------------------
// Kernel 2: flash attention — EXACT R2 structure (best verified: 84.6us),
// which is: 4 waves (2qh x 2th), K ping-pong LDS + single V LDS buffer, all
// staged via glds16, counted-vmcnt pipeline, 3 barriers/step. Two deltas:
//  (1) P packed DIRECTLY into pf[mt>>1][nt][(mt&1)*4+r] (algebra verified
//      numerically in R5's passing run) — deletes 64 halfword moves/step.
//  (2) s_setprio(1) around the pure-MFMA PV cluster (T5; blocks at
//      independent phases on a CU -> scheduler has something to arbitrate).
//  DO NOT: per-wave register V (R5: fragment-order gather = 16x64B segments
//  per load, +66us); 8-wave blocks (R4: barrier rendezvous overhead grows);
//  launch_bounds below ~128 VGPR budget (R3: accumulator spill catastrophe).
//  vmcnt ledger per wave/iter (K 4, V 4, mask 4; order pinned):
//    top: outstanding [K(j)4, V(j)4]; issue mask 4 -> 12; vmcnt(8) drains
//    K(j). B1. stageK(j+1) -> +4. softmax mask-use drains V(j)+mask
//    (vmcnt(4)), K(j+1) stays. explicit vmcnt(4) + B_mid: V(j) visible.
//    PV. B2. stageV(j+1). j=31: no issues, waits degrade to no-ops.
//  LDS: Ks0|Ks1 16K each + Vt 16K + Ll 256B = 49408; reduction aliases Lo.
// ---------------------------------------------------------------------------
__global__ __launch_bounds__(256)
void attention(const __bf16* __restrict__ Qb, const __bf16* __restrict__ Kb,
               const __bf16* __restrict__ vT, const float* __restrict__ mask,
               float* __restrict__ out)
{
  __shared__ char smem[49408];
  __bf16* Vt = (__bf16*)(smem + 32768);       // [64][128], swizzled+permuted-t
  float*  Ll = (float*)(smem + 49152);        // l partials (64 floats)
  float*  Lo = (float*)smem;                  // alias, end-reduction only

  const int tid  = threadIdx.x;
  const int wave = tid >> 6, lane = tid & 63;
  const int quad = lane >> 4, l16 = lane & 15;
  const int qh = wave >> 1;       // q-half
  const int th = wave & 1;        // t-half
  const int qb = blockIdx.x, h = blockIdx.y;
  const int q0 = qb * 64;
  const int qcol = h * 64;
  const int srow = lane >> 3, sg = lane & 7;
  const int vrow = lane >> 4, vs = lane & 15;

  bf16x8 qf[2][2];
  #pragma unroll
  for (int nt = 0; nt < 2; ++nt)
    #pragma unroll
    for (int kt = 0; kt < 2; ++kt)
      qf[nt][kt] = *reinterpret_cast<const bf16x8*>(
          Qb + (q0 + qh * 32 + nt * 16 + l16) * D + qcol + kt * 32 + quad * 8);

  floatx4 accO[4][2];
  #pragma unroll
  for (int wt = 0; wt < 4; ++wt)
    #pragma unroll
    for (int nt = 0; nt < 2; ++nt) accO[wt][nt] = (floatx4){0.f, 0.f, 0.f, 0.f};
  floatx4 accL[2];
  accL[0] = (floatx4){0.f, 0.f, 0.f, 0.f};
  accL[1] = (floatx4){0.f, 0.f, 0.f, 0.f};
  bf16x8 ones;
  #pragma unroll
  for (int e = 0; e < 8; ++e) ones[e] = (__bf16)1.0f;

  auto stageK = [&](int j, __bf16* dst) {
    #pragma unroll
    for (int it = 0; it < 4; ++it) {
      int rbase = it * 32 + wave * 8;
      int t = rbase + srow;
      glds16(Kb + (size_t)(j * 128 + t) * D + qcol + (sg ^ (t & 7)) * 8,
             dst + rbase * 64);
    }
  };
  auto stageV = [&](int j) {
    #pragma unroll
    for (int it = 0; it < 4; ++it) {
      int wbase = it * 16 + wave * 4;
      int w = wbase + vrow;
      glds16(vT + (size_t)(qcol + w) * S + j * 128 + (vs ^ (w & 7)) * 8,
             Vt + wbase * 128);
    }
  };

  // prologue: K(0), V(0) in flight
  stageK(0, (__bf16*)smem);
  stageV(0);

  for (int j = 0; j < 32; ++j) {
    // mask loads for this step (hoisted above the counted wait so the
    // compiler's mask-use wait drains V(j) but not K(j+1))
    floatx4 mv[4];
    #pragma unroll
    for (int mt = 0; mt < 4; ++mt)
      mv[mt] = *reinterpret_cast<const floatx4*>(
          mask + j * 128 + th * 64 + mt * 16 + quad * 4);

    asm volatile("s_waitcnt vmcnt(8)" ::: "memory");   // own K(j) drained
    __builtin_amdgcn_s_barrier();                      // B1: K(j) visible
    __builtin_amdgcn_sched_barrier(0);

    if (j < 31)                                        // prefetch next K
      stageK(j + 1, (__bf16*)(smem + (((j + 1) & 1) << 14)));
    __builtin_amdgcn_sched_barrier(0);

    const __bf16* Kc = (const __bf16*)(smem + ((j & 1) << 14));

    // S^T = K Q^T ; P = exp2(scale*S + mask2) packed DIRECTLY into pf.
    bf16x8 pf[2][2];
    #pragma unroll
    for (int mt = 0; mt < 4; ++mt) {
      int trow = th * 64 + mt * 16 + l16;
      bf16x8 kf[2];
      #pragma unroll
      for (int kt = 0; kt < 2; ++kt)
        kf[kt] = *reinterpret_cast<const bf16x8*>(
            &Kc[trow * 64 + ((((kt << 2) | quad) ^ (l16 & 7)) << 3)]);
      floatx4 am;   // (m-1)*10000*log2e ; exactly 0 when m==1
      #pragma unroll
      for (int r = 0; r < 4; ++r)
        am[r] = fmaf(mv[mt][r], 14426.9504f, -14426.9504f);
      #pragma unroll
      for (int nt = 0; nt < 2; ++nt) {
        floatx4 s = (floatx4){0.f, 0.f, 0.f, 0.f};
        #pragma unroll
        for (int kt = 0; kt < 2; ++kt)
          s = __builtin_amdgcn_mfma_f32_16x16x32_bf16(kf[kt], qf[nt][kt], s, 0, 0, 0);
        #pragma unroll
        for (int r = 0; r < 4; ++r)
          pf[mt >> 1][nt][(mt & 1) * 4 + r] = (__bf16)__builtin_amdgcn_exp2f(
              fmaf(s[r], 0.18033688f, am[r]));   // 0.125*log2e
      }
    }

    asm volatile("s_waitcnt vmcnt(4)" ::: "memory");   // V(j) drained; K(j+1) flies
    __builtin_amdgcn_s_barrier();                      // B_mid: V(j) visible
    __builtin_amdgcn_sched_barrier(0);

    // O^T += V^T P^T ; l via ones-MFMA. Pure-MFMA cluster -> setprio (T5).
    __builtin_amdgcn_s_setprio(1);
    #pragma unroll
    for (int u = 0; u < 2; ++u) {
      #pragma unroll
      for (int nt = 0; nt < 2; ++nt)
        accL[nt] = __builtin_amdgcn_mfma_f32_16x16x32_bf16(
            ones, pf[u][nt], accL[nt], 0, 0, 0);
      #pragma unroll
      for (int wt = 0; wt < 4; ++wt) {
        int w = wt * 16 + l16;
        bf16x8 vf = *reinterpret_cast<const bf16x8*>(
            &Vt[w * 128 + (((th * 8 + u * 4 + quad) ^ (w & 7)) << 3)]);
        #pragma unroll
        for (int nt = 0; nt < 2; ++nt)
          accO[wt][nt] = __builtin_amdgcn_mfma_f32_16x16x32_bf16(
              vf, pf[u][nt], accO[wt][nt], 0, 0, 0);
      }
    }
    __builtin_amdgcn_s_setprio(0);

    __builtin_amdgcn_s_barrier();                      // B2: Vt readers done
    __builtin_amdgcn_sched_barrier(0);
    if (j < 31) stageV(j + 1);                         // prefetch next V
    __builtin_amdgcn_sched_barrier(0);
  }

  // l for q = nt*16+l16 over this wave's 64 t: all 4 acc rows identical.
  float l_lane[2] = {accL[0][0], accL[1][0]};

  // ---- cross-wave reduction over t-halves ----
  __syncthreads();   // all Ks/Vt reads done; safe to alias Lo
  if (th == 1) {
    float* dst = Lo + qh * (64 * 33);
    #pragma unroll
    for (int wt = 0; wt < 4; ++wt)
      #pragma unroll
      for (int nt = 0; nt < 2; ++nt)
        #pragma unroll
        for (int r = 0; r < 4; ++r)
          dst[(wt * 16 + quad * 4 + r) * 33 + nt * 16 + l16] = accO[wt][nt][r];
    if (quad == 0) {
      #pragma unroll
      for (int nt = 0; nt < 2; ++nt)
        Ll[qh * 32 + nt * 16 + l16] = l_lane[nt];
    }
  }
  __syncthreads();
  if (th == 0) {
    const float* src = Lo + qh * (64 * 33);
    float l_tot[2];
    #pragma unroll
    for (int nt = 0; nt < 2; ++nt)
      l_tot[nt] = l_lane[nt] + Ll[qh * 32 + nt * 16 + l16];
    #pragma unroll
    for (int wt = 0; wt < 4; ++wt)
      #pragma unroll
      for (int nt = 0; nt < 2; ++nt) {
        floatx4 o;
        #pragma unroll
        for (int r = 0; r < 4; ++r)
          o[r] = (accO[wt][nt][r] +
                  src[(wt * 16 + quad * 4 + r) * 33 + nt * 16 + l16]) / l_tot[nt];
        int row = q0 + qh * 32 + nt * 16 + l16;
        int col = qcol + wt * 16 + quad * 4;
        *reinterpret_cast<floatx4*>(&out[row * D + col]) = o;
      }
  }
}

} // namespace

extern "C" void kernel_launch(void* const* d_in, const int* in_sizes, int n_in,
                              void* d_out, int out_size, void* d_ws, size_t ws_size,
                              hipStream_t stream) {
  const float *x = nullptr, *mask = nullptr, *Wq = nullptr, *bq = nullptr;
  for (int i = 0; i < n_in; ++i) {
    switch (in_sizes[i]) {
      case 3145728: x    = (const float*)d_in[i]; break;
      case 4096:    mask = (const float*)d_in[i]; break;
      case 1769472: Wq   = (const float*)d_in[i]; break;
      case 2304:    bq   = (const float*)d_in[i]; break;
      default: break;
    }
  }

  __bf16* xb = (__bf16*)d_out;               // bf16 scratch in d_out
  __bf16* WT = xb + (size_t)S * D;
  __bf16* Qb = (__bf16*)d_ws;
  __bf16* Kb = Qb + (size_t)S * D;
  __bf16* vT = Kb + (size_t)S * D;

  convert_all<<<3072 + 432, 256, 0, stream>>>(x, xb, Wq, WT);
  qkv_gemm   <<<dim3(S / 128, N3 / 96), 256, 0, stream>>>(xb, WT, bq, Qb, Kb, vT);
  attention  <<<dim3(S / 64, H), 256, 0, stream>>>(Qb, Kb, vT, mask, (float*)d_out);
}

// Round 7
// 165.094 us; speedup vs baseline: 1.3875x; 1.0011x over previous
//
#include <hip/hip_runtime.h>
#include <hip/hip_bf16.h>

namespace {
constexpr int S  = 4096;
constexpr int D  = 768;
constexpr int H  = 12;
constexpr int N3 = 2304;   // 3*D

typedef __bf16 bf16x4 __attribute__((ext_vector_type(4)));
typedef __bf16 bf16x8 __attribute__((ext_vector_type(8)));
typedef float  floatx4 __attribute__((ext_vector_type(4)));

// async global->LDS, 16B per lane; LDS dest = wave-uniform base + lane*16.
__device__ inline void glds16(const __bf16* g, __bf16* l) {
  __builtin_amdgcn_global_load_lds(
      (const __attribute__((address_space(1))) void*)(const void*)g,
      (__attribute__((address_space(3))) void*)(void*)l, 16, 0, 0);
}

// ---------------------------------------------------------------------------
// Kernel 0: merged converts. bid < 3072: x fp32 -> bf16 (1024 elems/block).
// Else: W [768][2304] fp32 -> WT [2304][768] bf16 via LDS tile transpose.
// ---------------------------------------------------------------------------
__global__ __launch_bounds__(256)
void convert_all(const float* __restrict__ x, __bf16* __restrict__ xb,
                 const float* __restrict__ W, __bf16* __restrict__ WT)
{
  const int bid = blockIdx.x;
  const int tid = threadIdx.x;
  if (bid < 3072) {
    const int i = (bid * 256 + tid) * 4;
    floatx4 v = *reinterpret_cast<const floatx4*>(x + i);
    bf16x4 b;
    #pragma unroll
    for (int e = 0; e < 4; ++e) b[e] = (__bf16)v[e];
    *reinterpret_cast<bf16x4*>(xb + i) = b;
  } else {
    __shared__ float T[64][65];
    const int b2 = bid - 3072;
    const int d0 = (b2 % 12) * 64, e0 = (b2 / 12) * 64;
    const int rr = tid >> 4, c4 = (tid & 15) * 4;
    #pragma unroll
    for (int it = 0; it < 4; ++it) {
      int d = it * 16 + rr;
      floatx4 v = *reinterpret_cast<const floatx4*>(W + (d0 + d) * N3 + e0 + c4);
      #pragma unroll
      for (int e = 0; e < 4; ++e) T[d][c4 + e] = v[e];
    }
    __syncthreads();
    #pragma unroll
    for (int it = 0; it < 4; ++it) {
      int e = it * 16 + rr;
      bf16x4 b;
      #pragma unroll
      for (int i = 0; i < 4; ++i) b[i] = (__bf16)T[c4 + i][e];
      *reinterpret_cast<bf16x4*>(WT + (e0 + e) * D + d0 + c4) = b;
    }
  }
}

// ---------------------------------------------------------------------------
// Kernel 1: QKV GEMM, 128x96 tile, grid 32x24 = 768 = 3/CU.  NEW this round:
// the K-loop is pipelined like attention's K path (validated R2/R6):
//  * BK=32, both tiles double-buffered IN-PLACE within the same 28 KB:
//    A0|A1 (8KB each, [128][32] swizzled) + B0|B1 (6KB each, [96][32]).
//    Occupancy unchanged (3 blocks/CU).
//  * One barrier per K-step: vmcnt(0) -> s_barrier -> issue stage(k+1) into
//    h^1 -> ds_read + 12 MFMA. The top barrier both publishes stage(k) and
//    retires readers of half h^1 (they finished compute(k-1) before it), so
//    stage(k+1)'s DMA flies across the whole compute phase instead of being
//    drained immediately (the old sync;stage;sync;compute = zero overlap).
//  * 64B-row swizzle: physical 16B slot = logical ^ ((row>>1)&3); read bank
//    spread = 2-way on b128 (free). Source col pre-swizzled per lane.
//  * B staging round 2 (rows 64..95) is waves 0,1 only (wave-uniform if);
//    vmcnt(0) is issue-count-independent, so the asymmetric ledger is safe.
//    B rows 96..127 of the tile don't exist; rounds never touch them.
// Q/K direct stores; V via swizzled-LDS transpose then coalesced 16B stores.
// ---------------------------------------------------------------------------
__global__ __launch_bounds__(256)
void qkv_gemm(const __bf16* __restrict__ xb, const __bf16* __restrict__ WT,
              const float* __restrict__ bq, __bf16* __restrict__ Qb,
              __bf16* __restrict__ Kb, __bf16* __restrict__ vT)
{
  __shared__ __bf16 smem[14336];  // A0[4096] A1[4096] B0[3072] B1[3072]; vts
  const int tid  = threadIdx.x;
  const int wave = tid >> 6, lane = tid & 63;
  const int quad = lane >> 4, l16 = lane & 15;
  const int m_base = (wave >> 1) * 64;
  const int n_base = (wave & 1) * 48;
  const int bm = blockIdx.x, bn = blockIdx.y;

  floatx4 acc[4][3];
  #pragma unroll
  for (int i = 0; i < 4; ++i)
    #pragma unroll
    for (int j = 0; j < 3; ++j) acc[i][j] = (floatx4){0.f, 0.f, 0.f, 0.f};

  // stage one BK=32 half-tile pair into half h
  auto stageA = [&](int k, int h) {
    #pragma unroll
    for (int it = 0; it < 2; ++it) {
      int r0 = it * 64 + wave * 16;
      int row = r0 + (lane >> 2);
      glds16(xb + (size_t)(bm * 128 + row) * D + k * 32
                + (((lane & 3) ^ ((row >> 1) & 3)) * 8),
             smem + h * 4096 + r0 * 32);
    }
  };
  auto stageB = [&](int k, int h) {
    #pragma unroll
    for (int it = 0; it < 2; ++it) {
      int r0 = it * 64 + wave * 16;
      if (r0 < 96) {
        int row = r0 + (lane >> 2);
        glds16(WT + (size_t)(bn * 96 + row) * D + k * 32
                  + (((lane & 3) ^ ((row >> 1) & 3)) * 8),
               smem + 8192 + h * 3072 + r0 * 32);
      }
    }
  };

  __builtin_amdgcn_sched_barrier(0);
  stageA(0, 0); stageB(0, 0);            // prologue
  __builtin_amdgcn_sched_barrier(0);

  for (int k = 0; k < 24; ++k) {
    const int h = k & 1;
    asm volatile("s_waitcnt vmcnt(0)" ::: "memory");   // stage(k) landed
    __builtin_amdgcn_s_barrier();                      // publish k / retire k-1
    __builtin_amdgcn_sched_barrier(0);

    if (k < 23) { stageA(k + 1, h ^ 1); stageB(k + 1, h ^ 1); }
    __builtin_amdgcn_sched_barrier(0);

    bf16x8 af[4], bfr[3];
    #pragma unroll
    for (int mt = 0; mt < 4; ++mt) {
      int m = m_base + mt * 16 + l16;
      af[mt] = *reinterpret_cast<const bf16x8*>(
          &smem[h * 4096 + m * 32 + ((quad ^ ((m >> 1) & 3)) << 3)]);
    }
    #pragma unroll
    for (int nt = 0; nt < 3; ++nt) {
      int n = n_base + nt * 16 + l16;
      bfr[nt] = *reinterpret_cast<const bf16x8*>(
          &smem[8192 + h * 3072 + n * 32 + ((quad ^ ((n >> 1) & 3)) << 3)]);
    }
    #pragma unroll
    for (int mt = 0; mt < 4; ++mt)
      #pragma unroll
      for (int nt = 0; nt < 3; ++nt)
        acc[mt][nt] = __builtin_amdgcn_mfma_f32_16x16x32_bf16(
            af[mt], bfr[nt], acc[mt][nt], 0, 0, 0);
  }

  if (bn < 16) {
    #pragma unroll
    for (int nt = 0; nt < 3; ++nt) {
      int col = bn * 96 + n_base + nt * 16 + l16;
      float bias = bq[col];
      #pragma unroll
      for (int mt = 0; mt < 4; ++mt) {
        int row = bm * 128 + m_base + mt * 16 + quad * 4;
        #pragma unroll
        for (int r = 0; r < 4; ++r) {
          __bf16 v = (__bf16)(acc[mt][nt][r] + bias);
          if (bn < 8) Qb[(row + r) * D + col] = v;
          else        Kb[(row + r) * D + (col - D)] = v;
        }
      }
    }
  } else {
    __syncthreads();
    __bf16* vts = smem;   // [w 96][t 128], addr = w*128 + (pos ^ ((w&7)<<3))
    #pragma unroll
    for (int nt = 0; nt < 3; ++nt) {
      int wl = n_base + nt * 16 + l16;
      float bias = bq[bn * 96 + wl];
      int sw = (wl & 7) << 3;
      #pragma unroll
      for (int mt = 0; mt < 4; ++mt) {
        #pragma unroll
        for (int r = 0; r < 4; ++r) {
          int tl = m_base + mt * 16 + quad * 4 + r;
          int pos = (tl & ~31) | (quad << 3) | ((tl & 16) >> 2) | r;
          vts[wl * 128 + (pos ^ sw)] = (__bf16)(acc[mt][nt][r] + bias);
        }
      }
    }
    __syncthreads();
    const int w0g = bn * 96 - 2 * D;
    #pragma unroll
    for (int it = 0; it < 6; ++it) {
      int c = it * 256 + tid;
      int wl = c >> 4, t0 = (c & 15) * 8;
      bf16x8 v = *reinterpret_cast<const bf16x8*>(
          &vts[wl * 128 + (t0 ^ ((wl & 7) << 3))]);
      *reinterpret_cast<bf16x8*>(
          &vT[(size_t)(w0g + wl) * S + bm * 128 + t0]) = v;
    }
  }
}

// ---------------------------------------------------------------------------
// Kernel 2: flash attention — R6 VERBATIM (best verified: 82.2us).
// 4 waves (2qh x 2th), K ping-pong LDS + single V LDS buffer via glds16,
// counted-vmcnt pipeline, direct pf packing, setprio around PV MFMA cluster.
// ---------------------------------------------------------------------------
__global__ __launch_bounds__(256)
void attention(const __bf16* __restrict__ Qb, const __bf16* __restrict__ Kb,
               const __bf16* __restrict__ vT, const float* __restrict__ mask,
               float* __restrict__ out)
{
  __shared__ char smem[49408];
  __bf16* Vt = (__bf16*)(smem + 32768);       // [64][128], swizzled+permuted-t
  float*  Ll = (float*)(smem + 49152);        // l partials (64 floats)
  float*  Lo = (float*)smem;                  // alias, end-reduction only

  const int tid  = threadIdx.x;
  const int wave = tid >> 6, lane = tid & 63;
  const int quad = lane >> 4, l16 = lane & 15;
  const int qh = wave >> 1;       // q-half
  const int th = wave & 1;        // t-half
  const int qb = blockIdx.x, h = blockIdx.y;
  const int q0 = qb * 64;
  const int qcol = h * 64;
  const int srow = lane >> 3, sg = lane & 7;
  const int vrow = lane >> 4, vs = lane & 15;

  bf16x8 qf[2][2];
  #pragma unroll
  for (int nt = 0; nt < 2; ++nt)
    #pragma unroll
    for (int kt = 0; kt < 2; ++kt)
      qf[nt][kt] = *reinterpret_cast<const bf16x8*>(
          Qb + (q0 + qh * 32 + nt * 16 + l16) * D + qcol + kt * 32 + quad * 8);

  floatx4 accO[4][2];
  #pragma unroll
  for (int wt = 0; wt < 4; ++wt)
    #pragma unroll
    for (int nt = 0; nt < 2; ++nt) accO[wt][nt] = (floatx4){0.f, 0.f, 0.f, 0.f};
  floatx4 accL[2];
  accL[0] = (floatx4){0.f, 0.f, 0.f, 0.f};
  accL[1] = (floatx4){0.f, 0.f, 0.f, 0.f};
  bf16x8 ones;
  #pragma unroll
  for (int e = 0; e < 8; ++e) ones[e] = (__bf16)1.0f;

  auto stageK = [&](int j, __bf16* dst) {
    #pragma unroll
    for (int it = 0; it < 4; ++it) {
      int rbase = it * 32 + wave * 8;
      int t = rbase + srow;
      glds16(Kb + (size_t)(j * 128 + t) * D + qcol + (sg ^ (t & 7)) * 8,
             dst + rbase * 64);
    }
  };
  auto stageV = [&](int j) {
    #pragma unroll
    for (int it = 0; it < 4; ++it) {
      int wbase = it * 16 + wave * 4;
      int w = wbase + vrow;
      glds16(vT + (size_t)(qcol + w) * S + j * 128 + (vs ^ (w & 7)) * 8,
             Vt + wbase * 128);
    }
  };

  // prologue: K(0), V(0) in flight
  stageK(0, (__bf16*)smem);
  stageV(0);

  for (int j = 0; j < 32; ++j) {
    // mask loads for this step (hoisted above the counted wait so the
    // compiler's mask-use wait drains V(j) but not K(j+1))
    floatx4 mv[4];
    #pragma unroll
    for (int mt = 0; mt < 4; ++mt)
      mv[mt] = *reinterpret_cast<const floatx4*>(
          mask + j * 128 + th * 64 + mt * 16 + quad * 4);

    asm volatile("s_waitcnt vmcnt(8)" ::: "memory");   // own K(j) drained
    __builtin_amdgcn_s_barrier();                      // B1: K(j) visible
    __builtin_amdgcn_sched_barrier(0);

    if (j < 31)                                        // prefetch next K
      stageK(j + 1, (__bf16*)(smem + (((j + 1) & 1) << 14)));
    __builtin_amdgcn_sched_barrier(0);

    const __bf16* Kc = (const __bf16*)(smem + ((j & 1) << 14));

    // S^T = K Q^T ; P = exp2(scale*S + mask2) packed DIRECTLY into pf.
    bf16x8 pf[2][2];
    #pragma unroll
    for (int mt = 0; mt < 4; ++mt) {
      int trow = th * 64 + mt * 16 + l16;
      bf16x8 kf[2];
      #pragma unroll
      for (int kt = 0; kt < 2; ++kt)
        kf[kt] = *reinterpret_cast<const bf16x8*>(
            &Kc[trow * 64 + ((((kt << 2) | quad) ^ (l16 & 7)) << 3)]);
      floatx4 am;   // (m-1)*10000*log2e ; exactly 0 when m==1
      #pragma unroll
      for (int r = 0; r < 4; ++r)
        am[r] = fmaf(mv[mt][r], 14426.9504f, -14426.9504f);
      #pragma unroll
      for (int nt = 0; nt < 2; ++nt) {
        floatx4 s = (floatx4){0.f, 0.f, 0.f, 0.f};
        #pragma unroll
        for (int kt = 0; kt < 2; ++kt)
          s = __builtin_amdgcn_mfma_f32_16x16x32_bf16(kf[kt], qf[nt][kt], s, 0, 0, 0);
        #pragma unroll
        for (int r = 0; r < 4; ++r)
          pf[mt >> 1][nt][(mt & 1) * 4 + r] = (__bf16)__builtin_amdgcn_exp2f(
              fmaf(s[r], 0.18033688f, am[r]));   // 0.125*log2e
      }
    }

    asm volatile("s_waitcnt vmcnt(4)" ::: "memory");   // V(j) drained; K(j+1) flies
    __builtin_amdgcn_s_barrier();                      // B_mid: V(j) visible
    __builtin_amdgcn_sched_barrier(0);

    // O^T += V^T P^T ; l via ones-MFMA. Pure-MFMA cluster -> setprio (T5).
    __builtin_amdgcn_s_setprio(1);
    #pragma unroll
    for (int u = 0; u < 2; ++u) {
      #pragma unroll
      for (int nt = 0; nt < 2; ++nt)
        accL[nt] = __builtin_amdgcn_mfma_f32_16x16x32_bf16(
            ones, pf[u][nt], accL[nt], 0, 0, 0);
      #pragma unroll
      for (int wt = 0; wt < 4; ++wt) {
        int w = wt * 16 + l16;
        bf16x8 vf = *reinterpret_cast<const bf16x8*>(
            &Vt[w * 128 + (((th * 8 + u * 4 + quad) ^ (w & 7)) << 3)]);
        #pragma unroll
        for (int nt = 0; nt < 2; ++nt)
          accO[wt][nt] = __builtin_amdgcn_mfma_f32_16x16x32_bf16(
              vf, pf[u][nt], accO[wt][nt], 0, 0, 0);
      }
    }
    __builtin_amdgcn_s_setprio(0);

    __builtin_amdgcn_s_barrier();                      // B2: Vt readers done
    __builtin_amdgcn_sched_barrier(0);
    if (j < 31) stageV(j + 1);                         // prefetch next V
    __builtin_amdgcn_sched_barrier(0);
  }

  // l for q = nt*16+l16 over this wave's 64 t: all 4 acc rows identical.
  float l_lane[2] = {accL[0][0], accL[1][0]};

  // ---- cross-wave reduction over t-halves ----
  __syncthreads();   // all Ks/Vt reads done; safe to alias Lo
  if (th == 1) {
    float* dst = Lo + qh * (64 * 33);
    #pragma unroll
    for (int wt = 0; wt < 4; ++wt)
      #pragma unroll
      for (int nt = 0; nt < 2; ++nt)
        #pragma unroll
        for (int r = 0; r < 4; ++r)
          dst[(wt * 16 + quad * 4 + r) * 33 + nt * 16 + l16] = accO[wt][nt][r];
    if (quad == 0) {
      #pragma unroll
      for (int nt = 0; nt < 2; ++nt)
        Ll[qh * 32 + nt * 16 + l16] = l_lane[nt];
    }
  }
  __syncthreads();
  if (th == 0) {
    const float* src = Lo + qh * (64 * 33);
    float l_tot[2];
    #pragma unroll
    for (int nt = 0; nt < 2; ++nt)
      l_tot[nt] = l_lane[nt] + Ll[qh * 32 + nt * 16 + l16];
    #pragma unroll
    for (int wt = 0; wt < 4; ++wt)
      #pragma unroll
      for (int nt = 0; nt < 2; ++nt) {
        floatx4 o;
        #pragma unroll
        for (int r = 0; r < 4; ++r)
          o[r] = (accO[wt][nt][r] +
                  src[(wt * 16 + quad * 4 + r) * 33 + nt * 16 + l16]) / l_tot[nt];
        int row = q0 + qh * 32 + nt * 16 + l16;
        int col = qcol + wt * 16 + quad * 4;
        *reinterpret_cast<floatx4*>(&out[row * D + col]) = o;
      }
  }
}

} // namespace

extern "C" void kernel_launch(void* const* d_in, const int* in_sizes, int n_in,
                              void* d_out, int out_size, void* d_ws, size_t ws_size,
                              hipStream_t stream) {
  const float *x = nullptr, *mask = nullptr, *Wq = nullptr, *bq = nullptr;
  for (int i = 0; i < n_in; ++i) {
    switch (in_sizes[i]) {
      case 3145728: x    = (const float*)d_in[i]; break;
      case 4096:    mask = (const float*)d_in[i]; break;
      case 1769472: Wq   = (const float*)d_in[i]; break;
      case 2304:    bq   = (const float*)d_in[i]; break;
      default: break;
    }
  }

  __bf16* xb = (__bf16*)d_out;               // bf16 scratch in d_out
  __bf16* WT = xb + (size_t)S * D;
  __bf16* Qb = (__bf16*)d_ws;
  __bf16* Kb = Qb + (size_t)S * D;
  __bf16* vT = Kb + (size_t)S * D;

  convert_all<<<3072 + 432, 256, 0, stream>>>(x, xb, Wq, WT);
  qkv_gemm   <<<dim3(S / 128, N3 / 96), 256, 0, stream>>>(xb, WT, bq, Qb, Kb, vT);
  attention  <<<dim3(S / 64, H), 256, 0, stream>>>(Qb, Kb, vT, mask, (float*)d_out);
}